// Round 17
// baseline (76.350 us; speedup 1.0000x reference)
//
#include <hip/hip_runtime.h>
#include <hip/hip_bf16.h>

typedef __attribute__((ext_vector_type(8))) short bf16x8;
typedef __attribute__((ext_vector_type(4))) float f32x4;

#define NPIX 6272          // 2*56*56
#define HW 56
#define HEADS 8
#define HD 32
#define KW 7
#define DIM 256
#define GDIM 768           // Q|K|V interleaved row stride
#define UK 112             // union keys: 8 rows x 14 cols
#define UKP 128            // padded keys
#define NX (NPIX * DIM)    // 1605632
#define NW (DIM * DIM)     // 65536

__device__ inline short f2bf(float f) {
    __hip_bfloat16 h = __float2bfloat16(f);
    return *(short*)&h;
}
__device__ inline float bf2f(short u) {
    union { unsigned int i; float f; } x;
    x.i = ((unsigned int)(unsigned short)u) << 16;
    return x.f;
}

__device__ __forceinline__ void gl_lds16(const short* g, short* l) {
    __builtin_amdgcn_global_load_lds(
        (const __attribute__((address_space(1))) unsigned int*)g,
        (__attribute__((address_space(3))) unsigned int*)l,
        16, 0, 0);
}

// ---------------- f32 -> bf16 conversion pre-pass ---------------------------
__global__ __launch_bounds__(256) void cvt_kernel(
    const float* __restrict__ X,
    const float* __restrict__ Wq, const float* __restrict__ Wk, const float* __restrict__ Wv,
    short* __restrict__ Xb, short* __restrict__ Wcb)
{
    const size_t e0 = ((size_t)blockIdx.x * 256 + threadIdx.x) * 8;
    const float* src; short* dst; size_t off;
    if (e0 < NX)                { src = X;  dst = Xb;        off = e0; }
    else if (e0 < NX + NW)      { src = Wq; dst = Wcb;       off = e0 - NX; }
    else if (e0 < NX + 2 * NW)  { src = Wk; dst = Wcb + NW;  off = e0 - NX - NW; }
    else                        { src = Wv; dst = Wcb + 2*NW; off = e0 - NX - 2 * NW; }
    float4 f0 = *(const float4*)(src + off);
    float4 f1 = *(const float4*)(src + off + 4);
    bf16x8 v;
    v[0]=f2bf(f0.x); v[1]=f2bf(f0.y); v[2]=f2bf(f0.z); v[3]=f2bf(f0.w);
    v[4]=f2bf(f1.x); v[5]=f2bf(f1.y); v[6]=f2bf(f1.z); v[7]=f2bf(f1.w);
    *(bf16x8*)(dst + off) = v;
}

// ---------------- Projection GEMM (round-10 exact form) ---------------------
__global__ __launch_bounds__(256, 2) void proj_kernel(
    const short* __restrict__ Xb,     // [6272][256] bf16
    const short* __restrict__ Wcb,    // [768][256] bf16
    const float* __restrict__ Bq, const float* __restrict__ Bk, const float* __restrict__ Bv,
    short* __restrict__ Y)            // [6272][768] bf16
{
    __shared__ short Ash[64 * 256];   // 32KB: [row][512B], chunk p holds global chunk p^(row&7)
    __shared__ short Bsh[64 * 256];

    const int id   = blockIdx.x;
    const int flat = (id & 7) * 147 + (id >> 3);
    const int bx   = flat / 12;              // row tile 0..97
    const int by   = flat - bx * 12;         // col tile 0..11

    const int tid  = threadIdx.x;
    const int wave = tid >> 6;
    const int lane = tid & 63;
    const int l15  = lane & 15;
    const int hi   = lane >> 4;

    const int brow = bx * 64;
    const int bcol = by * 64;

    #pragma unroll
    for (int i = 0; i < 8; ++i) {
        const int slot = tid + i * 256;          // 0..2047
        const int row  = slot >> 5;              // 0..63
        const int p    = slot & 31;              // 16B chunk within 512B row
        const int goff = ((p ^ (row & 7)) << 3); // elements (16B = 8 shorts)
        gl_lds16(Xb  + (size_t)(brow + row) * DIM + goff, Ash + slot * 8);
        gl_lds16(Wcb + (size_t)(bcol + row) * DIM + goff, Bsh + slot * 8);
    }
    __syncthreads();

    f32x4 acc[4];
    #pragma unroll
    for (int c = 0; c < 4; ++c) acc[c] = (f32x4){0.f, 0.f, 0.f, 0.f};

    const int arow = wave * 16 + l15;
    #pragma unroll
    for (int kk = 0; kk < 8; ++kk) {
        const int ch = kk * 4 + hi;              // 16B chunk index 0..31
        bf16x8 a = *(const bf16x8*)((char*)Ash + arow * 512 + ((ch ^ (arow & 7)) << 4));
        #pragma unroll
        for (int c = 0; c < 4; ++c) {
            const int bro = c * 16 + l15;
            bf16x8 b = *(const bf16x8*)((char*)Bsh + bro * 512 + ((ch ^ (bro & 7)) << 4));
            acc[c] = __builtin_amdgcn_mfma_f32_16x16x32_bf16(a, b, acc[c], 0, 0, 0);
        }
    }

    const int z = by >> 2;
    const float* Bi = (z == 0) ? Bq : (z == 1) ? Bk : Bv;
    const float scale = (z == 0) ? 0.17677669529663687f : 1.0f;
    #pragma unroll
    for (int c = 0; c < 4; ++c) {
        const int ocol = bcol + c * 16 + l15;
        const float bvv = Bi[ocol & 255];
        #pragma unroll
        for (int r = 0; r < 4; ++r) {
            const int row = brow + wave * 16 + hi * 4 + r;
            Y[(size_t)row * GDIM + ocol] = f2bf((acc[c][r] + bvv) * scale);
        }
    }
}

// ---------------- Neighborhood attention (round-16 version) -----------------
__global__ __launch_bounds__(256, 4) void nattn_kernel(
    const short* __restrict__ Yg,            // [NPIX][768] bf16: Q|K|V
    const float* __restrict__ rpb,           // [8][13][13] f32
    float* __restrict__ out)                 // [NPIX][256] f32
{
    __shared__ short VshT[128 * UKP];            // 32768 B: [d'][key], byte ^= ((d'&7)<<4)
    __shared__ __align__(16) short rpbs[8 * 169]; // 2704 B bf16

    const int id   = blockIdx.x;
    const int flat = (id & 7) * 98 + (id >> 3);
    const int bz   = flat / 392;
    int rem        = flat - bz * 392;
    const int ip   = rem / 14;
    rem           -= ip * 14;
    const int hg   = rem / 7;
    const int jt   = rem - hg * 7;

    const int tid  = threadIdx.x;
    const int wv   = tid >> 6;
    const int lane = tid & 63;
    const int l15  = lane & 15;
    const int hi   = lane >> 4;

    const int i0 = 2 * ip;
    const int j0 = jt * 8;
    const int r0 = min(max(i0 - 3, 0), HW - KW);
    const int c0 = min(max(j0 - 3, 0), HW - KW);

    const int h = hg * 4 + wv;               // this wave's head

    // ---- batch-issue V staging loads ---------------------------------------
    const int k2   = tid & 63;
    const int dblk = tid >> 6;
    const int keyL = 2 * k2, keyR = 2 * k2 + 1;
    const int aL = keyL / 14, cL = keyL - aL * 14;
    const int aR = keyR / 14, cR = keyR - aR * 14;
    const int giL = min(r0 + aL, HW - 1), gjL = min(c0 + cL, HW - 1);
    const int giR = min(r0 + aR, HW - 1), gjR = min(c0 + cR, HW - 1);
    const short* srcL = Yg + (size_t)((bz * HW + giL) * HW + gjL) * GDIM + 512 + hg * 128 + dblk * 32;
    const short* srcR = Yg + (size_t)((bz * HW + giR) * HW + gjR) * GDIM + 512 + hg * 128 + dblk * 32;
    bf16x8 vL[4], vR[4];
    #pragma unroll
    for (int m = 0; m < 4; ++m) {
        vL[m] = (keyL < UK) ? *(const bf16x8*)(srcL + m * 8) : (bf16x8){0,0,0,0,0,0,0,0};
        vR[m] = (keyR < UK) ? *(const bf16x8*)(srcR + m * 8) : (bf16x8){0,0,0,0,0,0,0,0};
    }

    const int qpix = (bz * HW + i0 + (l15 >> 3)) * HW + j0 + (l15 & 7);
    bf16x8 aq = *(const bf16x8*)(Yg + (size_t)qpix * GDIM + h * HD + hi * 8);

    const float4* rpb4 = (const float4*)rpb;
    float4 rv0 = rpb4[tid];
    float4 rv1 = (tid < 338 - 256) ? rpb4[tid + 256] : (float4){0.f,0.f,0.f,0.f};

    // ---- LDS writes --------------------------------------------------------
    #pragma unroll
    for (int m = 0; m < 4; ++m) {
        #pragma unroll
        for (int e = 0; e < 8; ++e) {
            const int d = dblk * 32 + m * 8 + e;          // d&7 == e
            const int w = ((int)(unsigned short)vL[m][e]) | ((int)vR[m][e] << 16);
            *(int*)((char*)VshT + d * 256 + ((4 * k2) ^ (e << 4))) = w;
        }
    }
    *(short4*)(&rpbs[tid * 4]) = make_short4(f2bf(rv0.x), f2bf(rv0.y), f2bf(rv0.z), f2bf(rv0.w));
    if (tid < 338 - 256)
        *(short4*)(&rpbs[(tid + 256) * 4]) = make_short4(f2bf(rv1.x), f2bf(rv1.y), f2bf(rv1.z), f2bf(rv1.w));
    __syncthreads();

    // ---- per-lane pixel (l15) metadata -------------------------------------
    const int iv = i0 + (l15 >> 3);
    const int jv = j0 + (l15 & 7);
    const int siv = min(max(iv - 3, 0), HW - KW);
    const int sjv = min(max(jv - 3, 0), HW - KW);
    const int bb  = (r0 - iv + 6) * 13 + (c0 - jv + 6);
    const int uai = siv - r0;
    const int ucj = sjv - c0;
    const f32x4 zf = {0.f, 0.f, 0.f, 0.f};

    // ---- scores (swapped): sacc[t] = K_tile^T x Q -> S^T -------------------
    f32x4 sacc[7];
    {
        bf16x8 kb[7];
        #pragma unroll
        for (int t = 0; t < 7; ++t) {
            const int key = t * 16 + l15;
            const int a = key / 14, c = key - a * 14;
            const int gi = min(r0 + a, HW - 1), gj = min(c0 + c, HW - 1);
            kb[t] = *(const bf16x8*)(Yg + (size_t)((bz * HW + gi) * HW + gj) * GDIM +
                                     256 + h * HD + hi * 8);
        }
        #pragma unroll
        for (int t = 0; t < 7; ++t)
            sacc[t] = __builtin_amdgcn_mfma_f32_16x16x32_bf16(kb[t], aq, zf, 0, 0, 0);
    }

    // ---- bias + mask (pixel fixed = l15; 28 keys in-register) --------------
    const short* rbh = rpbs + h * 169;
    float sc[7][4];
    #pragma unroll
    for (int t = 0; t < 7; ++t) {
        #pragma unroll
        for (int r = 0; r < 4; ++r) {
            const int key = t * 16 + (hi << 2) + r;
            const int a = key / 14, c = key - a * 14;
            const bool ok = ((unsigned)(a - uai) <= 6u) & ((unsigned)(c - ucj) <= 6u);
            const float s = sacc[t][r] + bf2f(rbh[bb + a * 13 + c]);
            sc[t][r] = ok ? s : -1e30f;
        }
    }

    // ---- softmax over keys for pixel l15 -----------------------------------
    float m = sc[0][0];
    #pragma unroll
    for (int t = 0; t < 7; ++t)
        #pragma unroll
        for (int r = 0; r < 4; ++r) m = fmaxf(m, sc[t][r]);
    m = fmaxf(m, __shfl_xor(m, 16));
    m = fmaxf(m, __shfl_xor(m, 32));

    float sm = 0.f;
    unsigned long long pk[7];
    #pragma unroll
    for (int t = 0; t < 7; ++t) {
        float e0 = __expf(sc[t][0] - m), e1 = __expf(sc[t][1] - m);
        float e2 = __expf(sc[t][2] - m), e3 = __expf(sc[t][3] - m);
        sm += (e0 + e1) + (e2 + e3);
        const unsigned u0 = (unsigned)(unsigned short)f2bf(e0) |
                            ((unsigned)(unsigned short)f2bf(e1) << 16);
        const unsigned u1 = (unsigned)(unsigned short)f2bf(e2) |
                            ((unsigned)(unsigned short)f2bf(e3) << 16);
        pk[t] = (unsigned long long)u0 | ((unsigned long long)u1 << 32);
    }
    sm += __shfl_xor(sm, 16);
    sm += __shfl_xor(sm, 32);

    // ---- PV: O^T = V^T x P^T; P^T B-frags via 64-bit shuffles --------------
    const int s0 = l15 + ((hi & 1) << 5);
    const bool hiSel = (hi >> 1) & 1;
    const int d0 = wv * 32 + l15;
    f32x4 o0 = zf, o1 = zf;
    #pragma unroll
    for (int kk = 0; kk < 4; ++kk) {
        unsigned long long a0 = __shfl(pk[2 * kk], s0, 64);
        unsigned long long b0 = __shfl(pk[2 * kk], s0 + 16, 64);
        unsigned long long a1 = 0ULL, b1 = 0ULL;
        if (2 * kk + 1 < 7) {
            a1 = __shfl(pk[2 * kk + 1], s0, 64);
            b1 = __shfl(pk[2 * kk + 1], s0 + 16, 64);
        }
        bf16x8 pa;
        ((unsigned long long*)&pa)[0] = hiSel ? a1 : a0;
        ((unsigned long long*)&pa)[1] = hiSel ? b1 : b0;

        const int koff = (kk * 64 + hi * 16) ^ ((l15 & 7) << 4);
        bf16x8 va0 = *(const bf16x8*)((char*)VshT + d0 * 256 + koff);
        bf16x8 va1 = *(const bf16x8*)((char*)VshT + (d0 + 16) * 256 + koff);
        o0 = __builtin_amdgcn_mfma_f32_16x16x32_bf16(va0, pa, o0, 0, 0, 0);
        o1 = __builtin_amdgcn_mfma_f32_16x16x32_bf16(va1, pa, o1, 0, 0, 0);
    }

    // ---- epilogue ----------------------------------------------------------
    const float inv = 1.f / sm;
    float4 w0, w1;
    w0.x = o0[0] * inv; w0.y = o0[1] * inv; w0.z = o0[2] * inv; w0.w = o0[3] * inv;
    w1.x = o1[0] * inv; w1.y = o1[1] * inv; w1.z = o1[2] * inv; w1.w = o1[3] * inv;
    float* orow = out + (size_t)qpix * DIM + h * HD + hi * 4;
    *(float4*)(orow)      = w0;
    *(float4*)(orow + 16) = w1;
}

extern "C" void kernel_launch(void* const* d_in, const int* in_sizes, int n_in,
                              void* d_out, int out_size, void* d_ws, size_t ws_size,
                              hipStream_t stream) {
    const float* hs = (const float*)d_in[0];
    const float* wq = (const float*)d_in[1];
    const float* bq = (const float*)d_in[2];
    const float* wk = (const float*)d_in[3];
    const float* bk = (const float*)d_in[4];
    const float* wv = (const float*)d_in[5];
    const float* bv = (const float*)d_in[6];
    const float* rpb = (const float*)d_in[7];

    short* Y   = (short*)d_ws;                       // [6272][768]
    short* Xb  = Y + (size_t)NPIX * GDIM;            // [6272][256]
    short* Wcb = Xb + (size_t)NX;                    // [768][256]

    // MEASUREMENT ROUND: every kernel launched 3x (all idempotent).
    // T = 3*(c+p+n) + OH; with R16's c+p+n+OH = 31.25:
    //   bodies = (T - 31.25)/2, OH = 31.25 - bodies.
    cvt_kernel<<<(NX + 3 * NW) / (256 * 8), 256, 0, stream>>>(hs, wq, wk, wv, Xb, Wcb);
    cvt_kernel<<<(NX + 3 * NW) / (256 * 8), 256, 0, stream>>>(hs, wq, wk, wv, Xb, Wcb);
    cvt_kernel<<<(NX + 3 * NW) / (256 * 8), 256, 0, stream>>>(hs, wq, wk, wv, Xb, Wcb);

    proj_kernel<<<1176, 256, 0, stream>>>(Xb, Wcb, bq, bk, bv, Y);
    proj_kernel<<<1176, 256, 0, stream>>>(Xb, Wcb, bq, bk, bv, Y);
    proj_kernel<<<1176, 256, 0, stream>>>(Xb, Wcb, bq, bk, bv, Y);

    nattn_kernel<<<784, 256, 0, stream>>>(Y, rpb, (float*)d_out);
    nattn_kernel<<<784, 256, 0, stream>>>(Y, rpb, (float*)d_out);
    nattn_kernel<<<784, 256, 0, stream>>>(Y, rpb, (float*)d_out);
}

// Round 18
// 27.460 us; speedup vs baseline: 2.7804x; 2.7804x over previous
//
#include <hip/hip_runtime.h>
#include <hip/hip_bf16.h>

typedef __attribute__((ext_vector_type(8))) short bf16x8;
typedef __attribute__((ext_vector_type(4))) float f32x4;

#define NPIX 6272          // 2*56*56
#define HW 56
#define HEADS 8
#define HD 32
#define KW 7
#define DIM 256
#define GDIM 768           // Q|K|V interleaved row stride
#define UK 112             // union keys: 8 rows x 14 cols
#define UKP 128            // padded keys

__device__ inline short f2bf(float f) {
    __hip_bfloat16 h = __float2bfloat16(f);
    return *(short*)&h;
}
__device__ inline float bf2f(short u) {
    union { unsigned int i; float f; } x;
    x.i = ((unsigned int)(unsigned short)u) << 16;
    return x.f;
}
__device__ inline bf16x8 pack8(float4 f0, float4 f1) {
    bf16x8 v;
    v[0]=f2bf(f0.x); v[1]=f2bf(f0.y); v[2]=f2bf(f0.z); v[3]=f2bf(f0.w);
    v[4]=f2bf(f1.x); v[5]=f2bf(f1.y); v[6]=f2bf(f1.z); v[7]=f2bf(f1.w);
    return v;
}

// ---------------- Fused cvt+proj GEMM: Y[6272][768] = X @ Wcat^T + b --------
// f32 inputs staged directly: batch-load A+W tiles as f32 (pre-swizzled
// source offsets), cvt in-register, 16B ds_write to the SAME LDS layout as
// before (read side byte-identical). (256,2) -> 256-VGPR cap, staging fits.
// 1-D grid 1176 = 8 XCDs x 147.
__global__ __launch_bounds__(256, 2) void proj_kernel(
    const float* __restrict__ X,
    const float* __restrict__ Wq, const float* __restrict__ Wk, const float* __restrict__ Wv,
    const float* __restrict__ Bq, const float* __restrict__ Bk, const float* __restrict__ Bv,
    short* __restrict__ Y)            // [6272][768] bf16
{
    __shared__ short Ash[64 * 256];   // 32KB: [row][512B], chunk p holds global chunk p^(row&7)
    __shared__ short Bsh[64 * 256];

    const int id   = blockIdx.x;
    const int flat = (id & 7) * 147 + (id >> 3);
    const int bx   = flat / 12;              // row tile 0..97
    const int by   = flat - bx * 12;         // col tile 0..11

    const int tid  = threadIdx.x;
    const int wave = tid >> 6;
    const int lane = tid & 63;
    const int l15  = lane & 15;
    const int hi   = lane >> 4;

    const int brow = bx * 64;
    const int bcol = by * 64;

    const int z = by >> 2;
    const float* Wb = (z == 0) ? Wq : (z == 1) ? Wk : Wv;
    const float* Bi = (z == 0) ? Bq : (z == 1) ? Bk : Bv;
    const float scale = (z == 0) ? 0.17677669529663687f : 1.0f;
    const int wcol0 = (bcol & 255);          // row offset within the selected W

    // ---- batch-issue ALL staging loads (f32, pre-swizzled offsets) ----
    float4 af[16], wf[16];
    #pragma unroll
    for (int i = 0; i < 8; ++i) {
        const int slot = tid + i * 256;          // 0..2047
        const int row  = slot >> 5;              // 0..63
        const int p    = slot & 31;              // 16B bf16 chunk (8 elements)
        const int ge   = ((p ^ (row & 7)) << 3); // element offset
        const float* asrc = X  + (size_t)(brow + row) * DIM + ge;
        const float* wsrc = Wb + (size_t)(wcol0 + row) * DIM + ge;
        af[2*i]   = *(const float4*)(asrc);
        af[2*i+1] = *(const float4*)(asrc + 4);
        wf[2*i]   = *(const float4*)(wsrc);
        wf[2*i+1] = *(const float4*)(wsrc + 4);
    }
    // ---- cvt + LDS writes (16B, conflict-free: consecutive slots) ----
    #pragma unroll
    for (int i = 0; i < 8; ++i) {
        const int slot = tid + i * 256;
        *(bf16x8*)(Ash + slot * 8) = pack8(af[2*i], af[2*i+1]);
        *(bf16x8*)(Bsh + slot * 8) = pack8(wf[2*i], wf[2*i+1]);
    }
    __syncthreads();

    f32x4 acc[4];
    #pragma unroll
    for (int c = 0; c < 4; ++c) acc[c] = (f32x4){0.f, 0.f, 0.f, 0.f};

    const int arow = wave * 16 + l15;
    #pragma unroll
    for (int kk = 0; kk < 8; ++kk) {
        const int ch = kk * 4 + hi;              // 16B chunk index 0..31
        bf16x8 a = *(const bf16x8*)((char*)Ash + arow * 512 + ((ch ^ (arow & 7)) << 4));
        #pragma unroll
        for (int c = 0; c < 4; ++c) {
            const int bro = c * 16 + l15;
            bf16x8 b = *(const bf16x8*)((char*)Bsh + bro * 512 + ((ch ^ (bro & 7)) << 4));
            acc[c] = __builtin_amdgcn_mfma_f32_16x16x32_bf16(a, b, acc[c], 0, 0, 0);
        }
    }

    #pragma unroll
    for (int c = 0; c < 4; ++c) {
        const int ocol = bcol + c * 16 + l15;
        const float bvv = Bi[ocol & 255];
        #pragma unroll
        for (int r = 0; r < 4; ++r) {
            const int row = brow + wave * 16 + hi * 4 + r;
            Y[(size_t)row * GDIM + ocol] = f2bf((acc[c][r] + bvv) * scale);
        }
    }
}

// ---------------- Neighborhood attention (round-16 version, unchanged) ------
__global__ __launch_bounds__(256, 4) void nattn_kernel(
    const short* __restrict__ Yg,            // [NPIX][768] bf16: Q|K|V
    const float* __restrict__ rpb,           // [8][13][13] f32
    float* __restrict__ out)                 // [NPIX][256] f32
{
    __shared__ short VshT[128 * UKP];            // 32768 B: [d'][key], byte ^= ((d'&7)<<4)
    __shared__ __align__(16) short rpbs[8 * 169]; // 2704 B bf16

    const int id   = blockIdx.x;
    const int flat = (id & 7) * 98 + (id >> 3);
    const int bz   = flat / 392;
    int rem        = flat - bz * 392;
    const int ip   = rem / 14;
    rem           -= ip * 14;
    const int hg   = rem / 7;
    const int jt   = rem - hg * 7;

    const int tid  = threadIdx.x;
    const int wv   = tid >> 6;
    const int lane = tid & 63;
    const int l15  = lane & 15;
    const int hi   = lane >> 4;

    const int i0 = 2 * ip;
    const int j0 = jt * 8;
    const int r0 = min(max(i0 - 3, 0), HW - KW);
    const int c0 = min(max(j0 - 3, 0), HW - KW);

    const int h = hg * 4 + wv;               // this wave's head

    // ---- batch-issue V staging loads ---------------------------------------
    const int k2   = tid & 63;
    const int dblk = tid >> 6;
    const int keyL = 2 * k2, keyR = 2 * k2 + 1;
    const int aL = keyL / 14, cL = keyL - aL * 14;
    const int aR = keyR / 14, cR = keyR - aR * 14;
    const int giL = min(r0 + aL, HW - 1), gjL = min(c0 + cL, HW - 1);
    const int giR = min(r0 + aR, HW - 1), gjR = min(c0 + cR, HW - 1);
    const short* srcL = Yg + (size_t)((bz * HW + giL) * HW + gjL) * GDIM + 512 + hg * 128 + dblk * 32;
    const short* srcR = Yg + (size_t)((bz * HW + giR) * HW + gjR) * GDIM + 512 + hg * 128 + dblk * 32;
    bf16x8 vL[4], vR[4];
    #pragma unroll
    for (int m = 0; m < 4; ++m) {
        vL[m] = (keyL < UK) ? *(const bf16x8*)(srcL + m * 8) : (bf16x8){0,0,0,0,0,0,0,0};
        vR[m] = (keyR < UK) ? *(const bf16x8*)(srcR + m * 8) : (bf16x8){0,0,0,0,0,0,0,0};
    }

    const int qpix = (bz * HW + i0 + (l15 >> 3)) * HW + j0 + (l15 & 7);
    bf16x8 aq = *(const bf16x8*)(Yg + (size_t)qpix * GDIM + h * HD + hi * 8);

    const float4* rpb4 = (const float4*)rpb;
    float4 rv0 = rpb4[tid];
    float4 rv1 = (tid < 338 - 256) ? rpb4[tid + 256] : (float4){0.f,0.f,0.f,0.f};

    // ---- LDS writes --------------------------------------------------------
    #pragma unroll
    for (int m = 0; m < 4; ++m) {
        #pragma unroll
        for (int e = 0; e < 8; ++e) {
            const int d = dblk * 32 + m * 8 + e;          // d&7 == e
            const int w = ((int)(unsigned short)vL[m][e]) | ((int)vR[m][e] << 16);
            *(int*)((char*)VshT + d * 256 + ((4 * k2) ^ (e << 4))) = w;
        }
    }
    *(short4*)(&rpbs[tid * 4]) = make_short4(f2bf(rv0.x), f2bf(rv0.y), f2bf(rv0.z), f2bf(rv0.w));
    if (tid < 338 - 256)
        *(short4*)(&rpbs[(tid + 256) * 4]) = make_short4(f2bf(rv1.x), f2bf(rv1.y), f2bf(rv1.z), f2bf(rv1.w));
    __syncthreads();

    // ---- per-lane pixel (l15) metadata -------------------------------------
    const int iv = i0 + (l15 >> 3);
    const int jv = j0 + (l15 & 7);
    const int siv = min(max(iv - 3, 0), HW - KW);
    const int sjv = min(max(jv - 3, 0), HW - KW);
    const int bb  = (r0 - iv + 6) * 13 + (c0 - jv + 6);
    const int uai = siv - r0;
    const int ucj = sjv - c0;
    const f32x4 zf = {0.f, 0.f, 0.f, 0.f};

    // ---- scores (swapped): sacc[t] = K_tile^T x Q -> S^T -------------------
    f32x4 sacc[7];
    {
        bf16x8 kb[7];
        #pragma unroll
        for (int t = 0; t < 7; ++t) {
            const int key = t * 16 + l15;
            const int a = key / 14, c = key - a * 14;
            const int gi = min(r0 + a, HW - 1), gj = min(c0 + c, HW - 1);
            kb[t] = *(const bf16x8*)(Yg + (size_t)((bz * HW + gi) * HW + gj) * GDIM +
                                     256 + h * HD + hi * 8);
        }
        #pragma unroll
        for (int t = 0; t < 7; ++t)
            sacc[t] = __builtin_amdgcn_mfma_f32_16x16x32_bf16(kb[t], aq, zf, 0, 0, 0);
    }

    // ---- bias + mask (pixel fixed = l15; 28 keys in-register) --------------
    const short* rbh = rpbs + h * 169;
    float sc[7][4];
    #pragma unroll
    for (int t = 0; t < 7; ++t) {
        #pragma unroll
        for (int r = 0; r < 4; ++r) {
            const int key = t * 16 + (hi << 2) + r;
            const int a = key / 14, c = key - a * 14;
            const bool ok = ((unsigned)(a - uai) <= 6u) & ((unsigned)(c - ucj) <= 6u);
            const float s = sacc[t][r] + bf2f(rbh[bb + a * 13 + c]);
            sc[t][r] = ok ? s : -1e30f;
        }
    }

    // ---- softmax over keys for pixel l15 -----------------------------------
    float m = sc[0][0];
    #pragma unroll
    for (int t = 0; t < 7; ++t)
        #pragma unroll
        for (int r = 0; r < 4; ++r) m = fmaxf(m, sc[t][r]);
    m = fmaxf(m, __shfl_xor(m, 16));
    m = fmaxf(m, __shfl_xor(m, 32));

    float sm = 0.f;
    unsigned long long pk[7];
    #pragma unroll
    for (int t = 0; t < 7; ++t) {
        float e0 = __expf(sc[t][0] - m), e1 = __expf(sc[t][1] - m);
        float e2 = __expf(sc[t][2] - m), e3 = __expf(sc[t][3] - m);
        sm += (e0 + e1) + (e2 + e3);
        const unsigned u0 = (unsigned)(unsigned short)f2bf(e0) |
                            ((unsigned)(unsigned short)f2bf(e1) << 16);
        const unsigned u1 = (unsigned)(unsigned short)f2bf(e2) |
                            ((unsigned)(unsigned short)f2bf(e3) << 16);
        pk[t] = (unsigned long long)u0 | ((unsigned long long)u1 << 32);
    }
    sm += __shfl_xor(sm, 16);
    sm += __shfl_xor(sm, 32);

    // ---- PV: O^T = V^T x P^T; P^T B-frags via 64-bit shuffles --------------
    const int s0 = l15 + ((hi & 1) << 5);
    const bool hiSel = (hi >> 1) & 1;
    const int d0 = wv * 32 + l15;
    f32x4 o0 = zf, o1 = zf;
    #pragma unroll
    for (int kk = 0; kk < 4; ++kk) {
        unsigned long long a0 = __shfl(pk[2 * kk], s0, 64);
        unsigned long long b0 = __shfl(pk[2 * kk], s0 + 16, 64);
        unsigned long long a1 = 0ULL, b1 = 0ULL;
        if (2 * kk + 1 < 7) {
            a1 = __shfl(pk[2 * kk + 1], s0, 64);
            b1 = __shfl(pk[2 * kk + 1], s0 + 16, 64);
        }
        bf16x8 pa;
        ((unsigned long long*)&pa)[0] = hiSel ? a1 : a0;
        ((unsigned long long*)&pa)[1] = hiSel ? b1 : b0;

        const int koff = (kk * 64 + hi * 16) ^ ((l15 & 7) << 4);
        bf16x8 va0 = *(const bf16x8*)((char*)VshT + d0 * 256 + koff);
        bf16x8 va1 = *(const bf16x8*)((char*)VshT + (d0 + 16) * 256 + koff);
        o0 = __builtin_amdgcn_mfma_f32_16x16x32_bf16(va0, pa, o0, 0, 0, 0);
        o1 = __builtin_amdgcn_mfma_f32_16x16x32_bf16(va1, pa, o1, 0, 0, 0);
    }

    // ---- epilogue ----------------------------------------------------------
    const float inv = 1.f / sm;
    float4 w0, w1;
    w0.x = o0[0] * inv; w0.y = o0[1] * inv; w0.z = o0[2] * inv; w0.w = o0[3] * inv;
    w1.x = o1[0] * inv; w1.y = o1[1] * inv; w1.z = o1[2] * inv; w1.w = o1[3] * inv;
    float* orow = out + (size_t)qpix * DIM + h * HD + hi * 4;
    *(float4*)(orow)      = w0;
    *(float4*)(orow + 16) = w1;
}

extern "C" void kernel_launch(void* const* d_in, const int* in_sizes, int n_in,
                              void* d_out, int out_size, void* d_ws, size_t ws_size,
                              hipStream_t stream) {
    const float* hs = (const float*)d_in[0];
    const float* wq = (const float*)d_in[1];
    const float* bq = (const float*)d_in[2];
    const float* wk = (const float*)d_in[3];
    const float* bk = (const float*)d_in[4];
    const float* wv = (const float*)d_in[5];
    const float* bv = (const float*)d_in[6];
    const float* rpb = (const float*)d_in[7];

    short* Y = (short*)d_ws;                         // [6272][768]

    proj_kernel<<<1176, 256, 0, stream>>>(hs, wq, wk, wv, bq, bk, bv, Y);

    nattn_kernel<<<784, 256, 0, stream>>>(Y, rpb, (float*)d_out);
}

// Round 19
// 26.877 us; speedup vs baseline: 2.8407x; 1.0217x over previous
//
#include <hip/hip_runtime.h>
#include <hip/hip_bf16.h>

typedef __attribute__((ext_vector_type(8))) short bf16x8;
typedef __attribute__((ext_vector_type(4))) float f32x4;

#define NPIX 6272          // 2*56*56
#define HW 56
#define HEADS 8
#define HD 32
#define KW 7
#define DIM 256
#define GDIM 768           // Q|K|V interleaved row stride
#define UK 112             // union keys: 8 rows x 14 cols
#define UKP 128            // padded keys

__device__ inline short f2bf(float f) {
    __hip_bfloat16 h = __float2bfloat16(f);
    return *(short*)&h;
}
__device__ inline float bf2f(short u) {
    union { unsigned int i; float f; } x;
    x.i = ((unsigned int)(unsigned short)u) << 16;
    return x.f;
}
__device__ inline bf16x8 pack8(float4 f0, float4 f1) {
    bf16x8 v;
    v[0]=f2bf(f0.x); v[1]=f2bf(f0.y); v[2]=f2bf(f0.z); v[3]=f2bf(f0.w);
    v[4]=f2bf(f1.x); v[5]=f2bf(f1.y); v[6]=f2bf(f1.z); v[7]=f2bf(f1.w);
    return v;
}

// ---------------- Fused cvt+proj GEMM, col-tile grouped ---------------------
// Block = (row-tile bx, col-group bg of 3 col-tiles). A staged once (f32->bf16,
// 32KB), B re-staged per col-tile (32KB, same buffer). Grid 392 = 8 XCDs x 49
// -> single dispatch round at 2 blocks/CU; X f32 traffic cut 3x.
__global__ __launch_bounds__(256, 2) void proj_kernel(
    const float* __restrict__ X,
    const float* __restrict__ Wq, const float* __restrict__ Wk, const float* __restrict__ Wv,
    const float* __restrict__ Bq, const float* __restrict__ Bk, const float* __restrict__ Bv,
    short* __restrict__ Y)            // [6272][768] bf16
{
    __shared__ short Ash[64 * 256];   // 32KB: [row][512B], chunk p holds global chunk p^(row&7)
    __shared__ short Bsh[64 * 256];   // 32KB, restaged per col-tile

    const int id   = blockIdx.x;
    const int flat = (id & 7) * 49 + (id >> 3);  // 392 = 8 * 49, bijective
    const int bx   = flat >> 2;              // row tile 0..97
    const int bg   = flat & 3;               // col group 0..3 (3 col-tiles each)

    const int tid  = threadIdx.x;
    const int wave = tid >> 6;
    const int lane = tid & 63;
    const int l15  = lane & 15;
    const int hi   = lane >> 4;

    const int brow = bx * 64;

    // ---- stage A once: batch f32 loads, cvt, write ----
    {
        float4 af[16];
        #pragma unroll
        for (int i = 0; i < 8; ++i) {
            const int slot = tid + i * 256;
            const int row  = slot >> 5;
            const int p    = slot & 31;
            const int ge   = ((p ^ (row & 7)) << 3);
            const float* asrc = X + (size_t)(brow + row) * DIM + ge;
            af[2*i]   = *(const float4*)(asrc);
            af[2*i+1] = *(const float4*)(asrc + 4);
        }
        #pragma unroll
        for (int i = 0; i < 8; ++i) {
            const int slot = tid + i * 256;
            *(bf16x8*)(Ash + slot * 8) = pack8(af[2*i], af[2*i+1]);
        }
    }

    const int arow = wave * 16 + l15;

    #pragma unroll
    for (int cg = 0; cg < 3; ++cg) {
        const int by   = bg * 3 + cg;        // col tile 0..11
        const int bcol = by * 64;
        const int z    = by >> 2;
        const float* Wb = (z == 0) ? Wq : (z == 1) ? Wk : Wv;
        const float* Bi = (z == 0) ? Bq : (z == 1) ? Bk : Bv;
        const float scale = (z == 0) ? 0.17677669529663687f : 1.0f;
        const int w0 = (by & 3) * 64;

        // ---- stage B col-tile ----
        {
            float4 wf[16];
            #pragma unroll
            for (int i = 0; i < 8; ++i) {
                const int slot = tid + i * 256;
                const int row  = slot >> 5;
                const int p    = slot & 31;
                const int ge   = ((p ^ (row & 7)) << 3);
                const float* wsrc = Wb + (size_t)(w0 + row) * DIM + ge;
                wf[2*i]   = *(const float4*)(wsrc);
                wf[2*i+1] = *(const float4*)(wsrc + 4);
            }
            #pragma unroll
            for (int i = 0; i < 8; ++i) {
                const int slot = tid + i * 256;
                *(bf16x8*)(Bsh + slot * 8) = pack8(wf[2*i], wf[2*i+1]);
            }
        }
        __syncthreads();

        f32x4 acc[4];
        #pragma unroll
        for (int c = 0; c < 4; ++c) acc[c] = (f32x4){0.f, 0.f, 0.f, 0.f};

        #pragma unroll
        for (int kk = 0; kk < 8; ++kk) {
            const int ch = kk * 4 + hi;
            bf16x8 a = *(const bf16x8*)((char*)Ash + arow * 512 + ((ch ^ (arow & 7)) << 4));
            #pragma unroll
            for (int c = 0; c < 4; ++c) {
                const int bro = c * 16 + l15;
                bf16x8 b = *(const bf16x8*)((char*)Bsh + bro * 512 + ((ch ^ (bro & 7)) << 4));
                acc[c] = __builtin_amdgcn_mfma_f32_16x16x32_bf16(a, b, acc[c], 0, 0, 0);
            }
        }

        #pragma unroll
        for (int c = 0; c < 4; ++c) {
            const int ocol = bcol + c * 16 + l15;
            const float bvv = Bi[ocol & 255];
            #pragma unroll
            for (int r = 0; r < 4; ++r) {
                const int row = brow + wave * 16 + hi * 4 + r;
                Y[(size_t)row * GDIM + ocol] = f2bf((acc[c][r] + bvv) * scale);
            }
        }
        if (cg < 2) __syncthreads();   // Bsh free before restage
    }
}

// ---------------- Neighborhood attention (round-16 version, unchanged) ------
__global__ __launch_bounds__(256, 4) void nattn_kernel(
    const short* __restrict__ Yg,            // [NPIX][768] bf16: Q|K|V
    const float* __restrict__ rpb,           // [8][13][13] f32
    float* __restrict__ out)                 // [NPIX][256] f32
{
    __shared__ short VshT[128 * UKP];            // 32768 B: [d'][key], byte ^= ((d'&7)<<4)
    __shared__ __align__(16) short rpbs[8 * 169]; // 2704 B bf16

    const int id   = blockIdx.x;
    const int flat = (id & 7) * 98 + (id >> 3);
    const int bz   = flat / 392;
    int rem        = flat - bz * 392;
    const int ip   = rem / 14;
    rem           -= ip * 14;
    const int hg   = rem / 7;
    const int jt   = rem - hg * 7;

    const int tid  = threadIdx.x;
    const int wv   = tid >> 6;
    const int lane = tid & 63;
    const int l15  = lane & 15;
    const int hi   = lane >> 4;

    const int i0 = 2 * ip;
    const int j0 = jt * 8;
    const int r0 = min(max(i0 - 3, 0), HW - KW);
    const int c0 = min(max(j0 - 3, 0), HW - KW);

    const int h = hg * 4 + wv;               // this wave's head

    // ---- batch-issue V staging loads ---------------------------------------
    const int k2   = tid & 63;
    const int dblk = tid >> 6;
    const int keyL = 2 * k2, keyR = 2 * k2 + 1;
    const int aL = keyL / 14, cL = keyL - aL * 14;
    const int aR = keyR / 14, cR = keyR - aR * 14;
    const int giL = min(r0 + aL, HW - 1), gjL = min(c0 + cL, HW - 1);
    const int giR = min(r0 + aR, HW - 1), gjR = min(c0 + cR, HW - 1);
    const short* srcL = Yg + (size_t)((bz * HW + giL) * HW + gjL) * GDIM + 512 + hg * 128 + dblk * 32;
    const short* srcR = Yg + (size_t)((bz * HW + giR) * HW + gjR) * GDIM + 512 + hg * 128 + dblk * 32;
    bf16x8 vL[4], vR[4];
    #pragma unroll
    for (int m = 0; m < 4; ++m) {
        vL[m] = (keyL < UK) ? *(const bf16x8*)(srcL + m * 8) : (bf16x8){0,0,0,0,0,0,0,0};
        vR[m] = (keyR < UK) ? *(const bf16x8*)(srcR + m * 8) : (bf16x8){0,0,0,0,0,0,0,0};
    }

    const int qpix = (bz * HW + i0 + (l15 >> 3)) * HW + j0 + (l15 & 7);
    bf16x8 aq = *(const bf16x8*)(Yg + (size_t)qpix * GDIM + h * HD + hi * 8);

    const float4* rpb4 = (const float4*)rpb;
    float4 rv0 = rpb4[tid];
    float4 rv1 = (tid < 338 - 256) ? rpb4[tid + 256] : (float4){0.f,0.f,0.f,0.f};

    // ---- LDS writes --------------------------------------------------------
    #pragma unroll
    for (int m = 0; m < 4; ++m) {
        #pragma unroll
        for (int e = 0; e < 8; ++e) {
            const int d = dblk * 32 + m * 8 + e;          // d&7 == e
            const int w = ((int)(unsigned short)vL[m][e]) | ((int)vR[m][e] << 16);
            *(int*)((char*)VshT + d * 256 + ((4 * k2) ^ (e << 4))) = w;
        }
    }
    *(short4*)(&rpbs[tid * 4]) = make_short4(f2bf(rv0.x), f2bf(rv0.y), f2bf(rv0.z), f2bf(rv0.w));
    if (tid < 338 - 256)
        *(short4*)(&rpbs[(tid + 256) * 4]) = make_short4(f2bf(rv1.x), f2bf(rv1.y), f2bf(rv1.z), f2bf(rv1.w));
    __syncthreads();

    // ---- per-lane pixel (l15) metadata -------------------------------------
    const int iv = i0 + (l15 >> 3);
    const int jv = j0 + (l15 & 7);
    const int siv = min(max(iv - 3, 0), HW - KW);
    const int sjv = min(max(jv - 3, 0), HW - KW);
    const int bb  = (r0 - iv + 6) * 13 + (c0 - jv + 6);
    const int uai = siv - r0;
    const int ucj = sjv - c0;
    const f32x4 zf = {0.f, 0.f, 0.f, 0.f};

    // ---- scores (swapped): sacc[t] = K_tile^T x Q -> S^T -------------------
    f32x4 sacc[7];
    {
        bf16x8 kb[7];
        #pragma unroll
        for (int t = 0; t < 7; ++t) {
            const int key = t * 16 + l15;
            const int a = key / 14, c = key - a * 14;
            const int gi = min(r0 + a, HW - 1), gj = min(c0 + c, HW - 1);
            kb[t] = *(const bf16x8*)(Yg + (size_t)((bz * HW + gi) * HW + gj) * GDIM +
                                     256 + h * HD + hi * 8);
        }
        #pragma unroll
        for (int t = 0; t < 7; ++t)
            sacc[t] = __builtin_amdgcn_mfma_f32_16x16x32_bf16(kb[t], aq, zf, 0, 0, 0);
    }

    // ---- bias + mask (pixel fixed = l15; 28 keys in-register) --------------
    const short* rbh = rpbs + h * 169;
    float sc[7][4];
    #pragma unroll
    for (int t = 0; t < 7; ++t) {
        #pragma unroll
        for (int r = 0; r < 4; ++r) {
            const int key = t * 16 + (hi << 2) + r;
            const int a = key / 14, c = key - a * 14;
            const bool ok = ((unsigned)(a - uai) <= 6u) & ((unsigned)(c - ucj) <= 6u);
            const float s = sacc[t][r] + bf2f(rbh[bb + a * 13 + c]);
            sc[t][r] = ok ? s : -1e30f;
        }
    }

    // ---- softmax over keys for pixel l15 -----------------------------------
    float m = sc[0][0];
    #pragma unroll
    for (int t = 0; t < 7; ++t)
        #pragma unroll
        for (int r = 0; r < 4; ++r) m = fmaxf(m, sc[t][r]);
    m = fmaxf(m, __shfl_xor(m, 16));
    m = fmaxf(m, __shfl_xor(m, 32));

    float sm = 0.f;
    unsigned long long pk[7];
    #pragma unroll
    for (int t = 0; t < 7; ++t) {
        float e0 = __expf(sc[t][0] - m), e1 = __expf(sc[t][1] - m);
        float e2 = __expf(sc[t][2] - m), e3 = __expf(sc[t][3] - m);
        sm += (e0 + e1) + (e2 + e3);
        const unsigned u0 = (unsigned)(unsigned short)f2bf(e0) |
                            ((unsigned)(unsigned short)f2bf(e1) << 16);
        const unsigned u1 = (unsigned)(unsigned short)f2bf(e2) |
                            ((unsigned)(unsigned short)f2bf(e3) << 16);
        pk[t] = (unsigned long long)u0 | ((unsigned long long)u1 << 32);
    }
    sm += __shfl_xor(sm, 16);
    sm += __shfl_xor(sm, 32);

    // ---- PV: O^T = V^T x P^T; P^T B-frags via 64-bit shuffles --------------
    const int s0 = l15 + ((hi & 1) << 5);
    const bool hiSel = (hi >> 1) & 1;
    const int d0 = wv * 32 + l15;
    f32x4 o0 = zf, o1 = zf;
    #pragma unroll
    for (int kk = 0; kk < 4; ++kk) {
        unsigned long long a0 = __shfl(pk[2 * kk], s0, 64);
        unsigned long long b0 = __shfl(pk[2 * kk], s0 + 16, 64);
        unsigned long long a1 = 0ULL, b1 = 0ULL;
        if (2 * kk + 1 < 7) {
            a1 = __shfl(pk[2 * kk + 1], s0, 64);
            b1 = __shfl(pk[2 * kk + 1], s0 + 16, 64);
        }
        bf16x8 pa;
        ((unsigned long long*)&pa)[0] = hiSel ? a1 : a0;
        ((unsigned long long*)&pa)[1] = hiSel ? b1 : b0;

        const int koff = (kk * 64 + hi * 16) ^ ((l15 & 7) << 4);
        bf16x8 va0 = *(const bf16x8*)((char*)VshT + d0 * 256 + koff);
        bf16x8 va1 = *(const bf16x8*)((char*)VshT + (d0 + 16) * 256 + koff);
        o0 = __builtin_amdgcn_mfma_f32_16x16x32_bf16(va0, pa, o0, 0, 0, 0);
        o1 = __builtin_amdgcn_mfma_f32_16x16x32_bf16(va1, pa, o1, 0, 0, 0);
    }

    // ---- epilogue ----------------------------------------------------------
    const float inv = 1.f / sm;
    float4 w0, w1;
    w0.x = o0[0] * inv; w0.y = o0[1] * inv; w0.z = o0[2] * inv; w0.w = o0[3] * inv;
    w1.x = o1[0] * inv; w1.y = o1[1] * inv; w1.z = o1[2] * inv; w1.w = o1[3] * inv;
    float* orow = out + (size_t)qpix * DIM + h * HD + hi * 4;
    *(float4*)(orow)      = w0;
    *(float4*)(orow + 16) = w1;
}

extern "C" void kernel_launch(void* const* d_in, const int* in_sizes, int n_in,
                              void* d_out, int out_size, void* d_ws, size_t ws_size,
                              hipStream_t stream) {
    const float* hs = (const float*)d_in[0];
    const float* wq = (const float*)d_in[1];
    const float* bq = (const float*)d_in[2];
    const float* wk = (const float*)d_in[3];
    const float* bk = (const float*)d_in[4];
    const float* wv = (const float*)d_in[5];
    const float* bv = (const float*)d_in[6];
    const float* rpb = (const float*)d_in[7];

    short* Y = (short*)d_ws;                         // [6272][768]

    proj_kernel<<<392, 256, 0, stream>>>(hs, wq, wk, wv, bq, bk, bv, Y);

    nattn_kernel<<<784, 256, 0, stream>>>(Y, rpb, (float*)d_out);
}